// Round 3
// baseline (438.267 us; speedup 1.0000x reference)
//
#include <hip/hip_runtime.h>

// ---------------------------------------------------------------------------
// RW_layer: random-walk graph kernel layer, fully factorized.
//   t_step[b,o] = (Σ_s w_step[b,s] x0[b,s,:]) · Zs_step[:,o]
//   x0 = sigmoid(F @ W_in + b_in)
//   w_0 = 1, w_1 = rowsum(adj), w_2 = rowsum(adj) @ adj      (adj symmetric)
//   Zs_0 = colsum(z0), Zs_1 = cA-weighted, Zs_2 = c2-weighted (A symmetric)
// then BN(batch stats) + sigmoid.
// R2: runtime dtype probe (p0) — input buffers may be fp32 or bf16; reading
// fp32 as bf16 shorts decodes random mantissa halves as NaN (~0.4%/value),
// which exactly reproduces the all-NaN output of R1/R2. All kernels branch
// (block-uniformly) on the probed flag. Internal math bf16-MFMA/fp32,
// stats fp64. NaN-sanitize on accv as a diagnostic net.
// ---------------------------------------------------------------------------

typedef short  vec8s  __attribute__((ext_vector_type(8)));
typedef short  vec4s  __attribute__((ext_vector_type(4)));
typedef float  f32x4  __attribute__((ext_vector_type(4)));
typedef unsigned short vec4us __attribute__((ext_vector_type(4)));

#define NB      32768      // batch
#define SS      16         // subgraph size
#define DIN     128
#define HH      64
#define OO      32
#define MM      16

__device__ __forceinline__ float bf2f(unsigned short u) {
    return __uint_as_float(((unsigned int)u) << 16);
}
__device__ __forceinline__ unsigned short f2bf(float f) {
    unsigned int u = __float_as_uint(f);
    unsigned int r = (u + 0x7fffu + ((u >> 16) & 1u)) >> 16;
    return (unsigned short)r;
}
template<bool F32>
__device__ __forceinline__ float ldv(const void* p, int i) {
    if (F32) return ((const float*)p)[i];
    return bf2f(((const unsigned short*)p)[i]);
}

// --------------------------- P0: dtype probe -------------------------------
// Scan first 4096 shorts of `features` decoded as bf16.
//  bf16-native N(0,1):    huge==0, zeros==0
//  fp32-native:           ~40% of low shorts huge (random mantissa bits)
//  fp32 of bf16-rounded:  low shorts all exactly zero
__global__ void p0_probe(const void* feat, int* flag) {
    __shared__ int chuge, czero;
    if (threadIdx.x == 0) { chuge = 0; czero = 0; }
    __syncthreads();
    const unsigned short* p = (const unsigned short*)feat;
    int h = 0, z = 0;
    for (int i = threadIdx.x; i < 4096; i += 64) {
        unsigned short u = p[i];
        unsigned e = (u >> 7) & 0xFFu;
        if (e >= 0x90u) h++;             // |v| >= 2^17: impossible for N(0,1)
        if ((u & 0x7FFFu) == 0) z++;     // exact zero
    }
    atomicAdd(&chuge, h);
    atomicAdd(&czero, z);
    __syncthreads();
    if (threadIdx.x == 0) *flag = (chuge > 8 || czero > 512) ? 1 : 0;
}

// A[i][j][o] of the symmetric hidden adjacency (relu of triu-packed params)
template<bool F32>
__device__ __forceinline__ float Aval(const void* ahS, int i, int j, int o) {
    if (i == j) return 0.f;
    int a = i < j ? i : j;
    int b = i < j ? j : i;
    int idx = a * 15 - ((a * (a - 1)) >> 1) + (b - a - 1);
    float v = ldv<F32>(ahS, idx * OO + o);
    return v > 0.f ? v : 0.f;
}

// --------------------------- K1: tiny prep ---------------------------------
// Builds Zcn[n=step*32+o][h] = Zs_step[h,o] (bf16) and Wt[h][k] = W_in[k][h],
// zeroes the fp64 stats accumulators. cA/c2 recomputed redundantly per block.
template<bool F32>
__device__ void k1_body(const void* fhP, const void* ahP, const void* WP,
                        short* ZcnS, short* WtS, float* cA, float* c2) {
    const int tid = threadIdx.x;
    for (int i = tid; i < MM * OO; i += 256) {
        int p = i >> 5, o = i & 31;
        float s = 0.f;
        for (int m = 0; m < MM; ++m) s += Aval<F32>(ahP, m, p, o);
        cA[i] = s;                      // cA[p,o] = Σ_m A[m,p,o]
    }
    __syncthreads();
    for (int i = tid; i < MM * OO; i += 256) {
        int qq = i >> 5, o = i & 31;
        float s = 0.f;
        for (int p = 0; p < MM; ++p) s += cA[p * OO + o] * Aval<F32>(ahP, p, qq, o);
        c2[i] = s;                      // c2[q,o] = Σ_p cA[p,o] A[p,q,o]
    }
    __syncthreads();
    for (int i = blockIdx.x * 256 + tid; i < 3 * OO * HH; i += 16 * 256) {
        int n = i >> 6, h = i & 63;
        int step = n >> 5, o = n & 31;
        float v = 0.f;
        for (int p = 0; p < MM; ++p) {
            float z = ldv<F32>(fhP, p * (HH * OO) + h * OO + o);
            float w = (step == 0) ? 1.f : (step == 1 ? cA[p * OO + o] : c2[p * OO + o]);
            v += w * z;
        }
        ZcnS[n * HH + h] = (short)f2bf(v);
    }
    for (int i = blockIdx.x * 256 + tid; i < DIN * HH; i += 16 * 256) {
        int h = i >> 7, k = i & 127;
        WtS[h * DIN + k] = (short)f2bf(ldv<F32>(WP, k * HH + h));  // W_in^T
    }
}

__global__ void k1_prep(const void* fhP, const void* ahP, const void* WP,
                        short* ZcnS, short* WtS, double* dstats,
                        const int* flag) {
    __shared__ float cA[MM * OO];
    __shared__ float c2[MM * OO];
    if (blockIdx.x == 0 && threadIdx.x < 64) dstats[threadIdx.x] = 0.0;
    if (*flag) k1_body<true>(fhP, ahP, WP, ZcnS, WtS, cA, c2);
    else       k1_body<false>(fhP, ahP, WP, ZcnS, WtS, cA, c2);
}

// --------------------------- K2: main kernel -------------------------------
// One wave per batch element per iteration. 512 blocks * 4 waves = 2048 waves,
// grid-stride *16 (uniform trip count -> in-loop barriers are legal).
// MFMA 16x16x32 bf16:
//   A-frag: A[m=lane&15][k=(lane>>4)*8+j], B-frag: B[k=(lane>>4)*8+j][n=lane&15]
//   C/D:    C[row=(lane>>4)*4+reg][col=lane&15]   (m89-verified)
template<bool F32>
__device__ void k2_body(const void* adjP, const void* featP, const void* binP,
                        const short* ZcnS, const short* WtS, float* accOut,
                        double* dstats, short* myx0, float* bsum, float* bsqs) {
    const int tid  = threadIdx.x;
    const int lane = tid & 63;
    const int hl   = lane & 15;
    const int q    = lane >> 4;

    // persistent B-frags: W (16) + Zcn (12), loaded once
    vec8s Wfrag[4][4];
    for (int kt = 0; kt < 4; ++kt)
        for (int nt = 0; nt < 4; ++nt)
            Wfrag[kt][nt] = *(const vec8s*)(WtS + (nt * 16 + hl) * DIN + kt * 32 + q * 8);
    vec8s Zfrag[2][6];
    for (int kt = 0; kt < 2; ++kt)
        for (int t = 0; t < 6; ++t)
            Zfrag[kt][t] = *(const vec8s*)(ZcnS + (t * 16 + hl) * HH + kt * 32 + q * 8);
    float biasv[4];
    for (int nt = 0; nt < 4; ++nt) biasv[nt] = ldv<F32>(binP, nt * 16 + hl);

    const f32x4 z4 = {0.f, 0.f, 0.f, 0.f};
    float ls = 0.f, lss = 0.f;
    const int wgid = blockIdx.x * 4 + (tid >> 6);

    for (int b = wgid; b < NB; b += 2048) {
        // ---- loads: adj row chunk + features A-frags ----
        float a0, a1, a2, a3;
        vec8s af[4];
        if (F32) {
            f32x4 av = *(const f32x4*)((const float*)adjP + b * (SS * SS) + lane * 4);
            a0 = av[0]; a1 = av[1]; a2 = av[2]; a3 = av[3];
            const float* fb = (const float*)featP + b * (SS * DIN) + hl * DIN + q * 8;
            for (int kt = 0; kt < 4; ++kt) {
                f32x4 lo = *(const f32x4*)(fb + kt * 32);
                f32x4 hi = *(const f32x4*)(fb + kt * 32 + 4);
                vec8s v;
                for (int j = 0; j < 4; ++j) {
                    v[j]     = (short)f2bf(lo[j]);
                    v[4 + j] = (short)f2bf(hi[j]);
                }
                af[kt] = v;
            }
        } else {
            vec4s av = *(const vec4s*)((const short*)adjP + b * (SS * SS) + lane * 4);
            a0 = bf2f((unsigned short)av.x); a1 = bf2f((unsigned short)av.y);
            a2 = bf2f((unsigned short)av.z); a3 = bf2f((unsigned short)av.w);
            const short* fb = (const short*)featP + b * (SS * DIN) + hl * DIN + q * 8;
            for (int kt = 0; kt < 4; ++kt) af[kt] = *(const vec8s*)(fb + kt * 32);
        }

        // ---- r = rowsum(adj), w2 = r @ adj (adj symmetric) ----
        // lane holds adj[i][4c+t], i=lane>>2, c=lane&3
        float rsum = a0 + a1 + a2 + a3;
        rsum += __shfl_xor(rsum, 1);
        rsum += __shfl_xor(rsum, 2);            // r[i] at lanes 4i..4i+3
        int cg = lane & 3;
        float rr0 = __shfl(rsum, cg * 16 + 0);  // r[4c+t] lives at lane (4c+t)*4
        float rr1 = __shfl(rsum, cg * 16 + 4);
        float rr2 = __shfl(rsum, cg * 16 + 8);
        float rr3 = __shfl(rsum, cg * 16 + 12);
        float p = a0 * rr0 + a1 * rr1 + a2 * rr2 + a3 * rr3;
        p += __shfl_xor(p, 1);
        p += __shfl_xor(p, 2);                  // w2[i]
        float w1q[4], w2q[4];                   // weights for s = q*4+reg (C rows)
        for (int reg = 0; reg < 4; ++reg) {
            int src = q * 16 + reg * 4;
            w1q[reg] = __shfl(rsum, src);
            w2q[reg] = __shfl(p, src);
        }

        // ---- GEMM1: x0pre = F @ W_in   (16x128 @ 128x64, 16 MFMAs) ----
        f32x4 c1[4] = {z4, z4, z4, z4};
        for (int nt = 0; nt < 4; ++nt)
            for (int kt = 0; kt < 4; ++kt)
                c1[nt] = __builtin_amdgcn_mfma_f32_16x16x32_bf16(af[kt], Wfrag[kt][nt], c1[nt], 0, 0, 0);

        // ---- sigmoid -> bf16, transpose C-layout -> (s,h) rows in LDS ----
        for (int nt = 0; nt < 4; ++nt)
            for (int reg = 0; reg < 4; ++reg) {
                float x = c1[nt][reg] + biasv[nt];
                float sg = 1.f / (1.f + __expf(-x));
                myx0[(q * 4 + reg) * 72 + nt * 16 + hl] = (short)f2bf(sg);
            }
        __syncthreads();   // order: transpose stores -> A-frag reads

        // ---- GEMM2: P = x0 @ Zcn^T   (16x64 @ 64x96, 12 MFMAs) ----
        vec8s a2lo = *(const vec8s*)(myx0 + hl * 72 + q * 8);
        vec8s a2hi = *(const vec8s*)(myx0 + hl * 72 + 32 + q * 8);
        __syncthreads();   // order: A-frag reads -> next iteration's stores
        f32x4 cp[6] = {z4, z4, z4, z4, z4, z4};
        for (int t = 0; t < 6; ++t)
            cp[t] = __builtin_amdgcn_mfma_f32_16x16x32_bf16(a2lo, Zfrag[0][t], cp[t], 0, 0, 0);
        for (int t = 0; t < 6; ++t)
            cp[t] = __builtin_amdgcn_mfma_f32_16x16x32_bf16(a2hi, Zfrag[1][t], cp[t], 0, 0, 0);

        // ---- weighted s-reduction per tile t; n' = t*16+hl, step = t>>1 ----
        float parts[6];
        for (int t = 0; t < 6; ++t) {
            int step = t >> 1;
            float v;
            if (step == 0)      v = cp[t][0] + cp[t][1] + cp[t][2] + cp[t][3];
            else if (step == 1) v = cp[t][0]*w1q[0] + cp[t][1]*w1q[1] + cp[t][2]*w1q[2] + cp[t][3]*w1q[3];
            else                v = cp[t][0]*w2q[0] + cp[t][1]*w2q[1] + cp[t][2]*w2q[2] + cp[t][3]*w2q[3];
            v += __shfl_xor(v, 16);
            v += __shfl_xor(v, 32);
            parts[t] = v;
        }
        float accA = parts[0] + parts[2] + parts[4];   // o = hl
        float accB = parts[1] + parts[3] + parts[5];   // o = 16 + hl
        float accv = ((lane >> 4) & 1) ? accB : accA;  // o = lane & 31 (dup x2)
        accv *= (1.f / 3.f);
        accv = __builtin_isnan(accv) ? 0.f : accv;     // diagnostic net
        if (lane < OO) accOut[b * OO + lane] = accv;
        ls  += accv;
        lss += accv * accv;
    }

    // ---- BN batch statistics: wave -> block(LDS) -> global(fp64 atomics) ----
    if (lane < OO) {
        atomicAdd(&bsum[lane], ls);
        atomicAdd(&bsqs[lane], lss);
    }
    __syncthreads();
    if (tid < OO) {
        atomicAdd(&dstats[tid],      (double)bsum[tid]);
        atomicAdd(&dstats[OO + tid], (double)bsqs[tid]);
    }
}

__global__ __launch_bounds__(256, 2) void k2_main(
    const void* adjP, const void* featP, const void* binP,
    const short* ZcnS, const short* WtS, float* accOut,
    double* dstats, const int* flag) {
    __shared__ __align__(16) short x0buf[4][SS * 72];
    __shared__ float bsum[OO];
    __shared__ float bsqs[OO];
    const int tid = threadIdx.x;
    if (tid < OO) { bsum[tid] = 0.f; bsqs[tid] = 0.f; }
    __syncthreads();
    short* myx0 = x0buf[tid >> 6];
    if (*flag) k2_body<true>(adjP, featP, binP, ZcnS, WtS, accOut, dstats, myx0, bsum, bsqs);
    else       k2_body<false>(adjP, featP, binP, ZcnS, WtS, accOut, dstats, myx0, bsum, bsqs);
}

// --------------------------- K3: BN scale/shift ----------------------------
__global__ void k3_stats(const double* __restrict__ dstats,
                         const void* gammaP, const void* betaP,
                         float* __restrict__ scaleArr, float* __restrict__ shiftArr,
                         const int* flag) {
    int o = threadIdx.x;
    if (o >= OO) return;
    double mean = dstats[o] * (1.0 / (double)NB);
    double ex2  = dstats[OO + o] * (1.0 / (double)NB);
    double var  = ex2 - mean * mean;
    if (var < 0.0) var = 0.0;
    double inv  = 1.0 / sqrt(var + 1e-5);
    float g, be;
    if (*flag) { g = ldv<true>(gammaP, o);  be = ldv<true>(betaP, o); }
    else       { g = ldv<false>(gammaP, o); be = ldv<false>(betaP, o); }
    float scale = g * (float)inv;
    scaleArr[o] = scale;
    shiftArr[o] = be - (float)(mean * inv) * g;
}

// --------------------------- K4: BN apply + sigmoid ------------------------
__global__ __launch_bounds__(256) void k4_out(const float* __restrict__ acc,
                                              const float* __restrict__ scaleArr,
                                              const float* __restrict__ shiftArr,
                                              void* out, const int* flag) {
    int i = (blockIdx.x * 256 + threadIdx.x) * 4;
    int o0 = i & 31;
    f32x4 a  = *(const f32x4*)(acc + i);
    f32x4 sc = *(const f32x4*)(scaleArr + o0);
    f32x4 sh = *(const f32x4*)(shiftArr + o0);
    float r[4];
    for (int j = 0; j < 4; ++j) {
        float z = a[j] * sc[j] + sh[j];
        r[j] = 1.f / (1.f + __expf(-z));
    }
    if (*flag) {
        f32x4 w;
        for (int j = 0; j < 4; ++j) w[j] = r[j];
        *(f32x4*)((float*)out + i) = w;
    } else {
        vec4us w;
        for (int j = 0; j < 4; ++j) w[j] = f2bf(r[j]);
        *(vec4us*)((unsigned short*)out + i) = w;
    }
}

// ---------------------------------------------------------------------------
extern "C" void kernel_launch(void* const* d_in, const int* in_sizes, int n_in,
                              void* d_out, int out_size, void* d_ws, size_t ws_size,
                              hipStream_t stream) {
    const void* adjP   = d_in[0];  // (B,16,16)
    const void* featP  = d_in[1];  // (B,16,128)
    const void* WP     = d_in[2];  // (128,64)
    const void* binP   = d_in[3];  // (64,)
    const void* fhP    = d_in[4];  // (16,64,32)
    const void* ahP    = d_in[5];  // (120,32)
    const void* gammaP = d_in[6];  // (32,)
    const void* betaP  = d_in[7];  // (32,)

    char* ws = (char*)d_ws;
    float*  accOut   = (float*)(ws);                    // 32768*32*4 = 4194304 B
    short*  ZcnS     = (short*)(ws + 4194304);          // 96*64*2   = 12288 B
    short*  WtS      = (short*)(ws + 4206592);          // 64*128*2  = 16384 B
    double* dstats   = (double*)(ws + 4222976);         // 64*8      = 512 B
    float*  scaleArr = (float*)(ws + 4223488);          // 32*4
    float*  shiftArr = (float*)(ws + 4223616);          // 32*4
    int*    flag     = (int*)(ws + 4223744);            // 4 B

    hipLaunchKernelGGL(p0_probe, dim3(1),    dim3(64),  0, stream, featP, flag);
    hipLaunchKernelGGL(k1_prep,  dim3(16),   dim3(256), 0, stream,
                       fhP, ahP, WP, ZcnS, WtS, dstats, flag);
    hipLaunchKernelGGL(k2_main,  dim3(512),  dim3(256), 0, stream,
                       adjP, featP, binP, ZcnS, WtS, accOut, dstats, flag);
    hipLaunchKernelGGL(k3_stats, dim3(1),    dim3(32),  0, stream,
                       dstats, gammaP, betaP, scaleArr, shiftArr, flag);
    hipLaunchKernelGGL(k4_out,   dim3(1024), dim3(256), 0, stream,
                       accOut, scaleArr, shiftArr, d_out, flag);
}

// Round 4
// 427.523 us; speedup vs baseline: 1.0251x; 1.0251x over previous
//
#include <hip/hip_runtime.h>

// ---------------------------------------------------------------------------
// RW_layer: random-walk graph kernel layer, fully factorized.
//   t_step[b,o] = (Σ_s w_step[b,s] x0[b,s,:]) · Zs_step[:,o]
//   x0 = sigmoid(F @ W_in + b_in)
//   w_0 = 1, w_1 = rowsum(adj), w_2 = rowsum(adj) @ adj      (adj symmetric)
// then BN(batch stats) + sigmoid.
// R3 result: PASSED (absmax 3.9e-3) — inputs are fp32 (probe flag=1).
// R4: (a) k2 in-loop __syncthreads -> __threadfence_block (x0buf is
// wave-private; barrier's vmcnt(0) drain halved memory duty cycle),
// (b) 5 launches -> 3 (probe folded into k1, k3 folded into k4),
// (c) cheaper fp32->bf16 pair-packing for the GEMM1 A-frags.
// ---------------------------------------------------------------------------

typedef short  vec8s  __attribute__((ext_vector_type(8)));
typedef short  vec4s  __attribute__((ext_vector_type(4)));
typedef float  f32x4  __attribute__((ext_vector_type(4)));
typedef unsigned short vec4us __attribute__((ext_vector_type(4)));

#define NB      32768      // batch
#define SS      16         // subgraph size
#define DIN     128
#define HH      64
#define OO      32
#define MM      16

__device__ __forceinline__ float bf2f(unsigned short u) {
    return __uint_as_float(((unsigned int)u) << 16);
}
__device__ __forceinline__ unsigned short f2bf(float f) {   // RNE (k1 only)
    unsigned int u = __float_as_uint(f);
    unsigned int r = (u + 0x7fffu + ((u >> 16) & 1u)) >> 16;
    return (unsigned short)r;
}
template<bool F32>
__device__ __forceinline__ float ldv(const void* p, int i) {
    if (F32) return ((const float*)p)[i];
    return bf2f(((const unsigned short*)p)[i]);
}
// pack 8 fp32 -> 8 bf16 (round-half-up), order-preserving
__device__ __forceinline__ vec8s pack8(f32x4 lo, f32x4 hi) {
    union { unsigned int u[4]; vec8s v; } r;
    unsigned int a0 = __float_as_uint(lo[0]) + 0x8000u;
    unsigned int a1 = __float_as_uint(lo[1]) + 0x8000u;
    unsigned int a2 = __float_as_uint(lo[2]) + 0x8000u;
    unsigned int a3 = __float_as_uint(lo[3]) + 0x8000u;
    unsigned int b0 = __float_as_uint(hi[0]) + 0x8000u;
    unsigned int b1 = __float_as_uint(hi[1]) + 0x8000u;
    unsigned int b2 = __float_as_uint(hi[2]) + 0x8000u;
    unsigned int b3 = __float_as_uint(hi[3]) + 0x8000u;
    r.u[0] = (a0 >> 16) | (a1 & 0xFFFF0000u);
    r.u[1] = (a2 >> 16) | (a3 & 0xFFFF0000u);
    r.u[2] = (b0 >> 16) | (b1 & 0xFFFF0000u);
    r.u[3] = (b2 >> 16) | (b3 & 0xFFFF0000u);
    return r.v;
}

// A[i][j][o] of the symmetric hidden adjacency (relu of triu-packed params)
template<bool F32>
__device__ __forceinline__ float Aval(const void* ahS, int i, int j, int o) {
    if (i == j) return 0.f;
    int a = i < j ? i : j;
    int b = i < j ? j : i;
    int idx = a * 15 - ((a * (a - 1)) >> 1) + (b - a - 1);
    float v = ldv<F32>(ahS, idx * OO + o);
    return v > 0.f ? v : 0.f;
}

// --------------------------- K1: prep + dtype probe ------------------------
// Builds Zcn[n=step*32+o][h] = Zs_step[h,o] (bf16) and Wt[h][k] = W_in[k][h],
// zeroes fp64 stats. Each block probes the input dtype itself (4096 shorts of
// features decoded as bf16: fp32-native data shows ~40% "huge" low-shorts).
template<bool F32>
__device__ void k1_body(const void* fhP, const void* ahP, const void* WP,
                        short* ZcnS, short* WtS, float* cA, float* c2) {
    const int tid = threadIdx.x;
    for (int i = tid; i < MM * OO; i += 256) {
        int p = i >> 5, o = i & 31;
        float s = 0.f;
        for (int m = 0; m < MM; ++m) s += Aval<F32>(ahP, m, p, o);
        cA[i] = s;                      // cA[p,o] = Σ_m A[m,p,o]
    }
    __syncthreads();
    for (int i = tid; i < MM * OO; i += 256) {
        int qq = i >> 5, o = i & 31;
        float s = 0.f;
        for (int p = 0; p < MM; ++p) s += cA[p * OO + o] * Aval<F32>(ahP, p, qq, o);
        c2[i] = s;                      // c2[q,o] = Σ_p cA[p,o] A[p,q,o]
    }
    __syncthreads();
    for (int i = blockIdx.x * 256 + tid; i < 3 * OO * HH; i += 16 * 256) {
        int n = i >> 6, h = i & 63;
        int step = n >> 5, o = n & 31;
        float v = 0.f;
        for (int p = 0; p < MM; ++p) {
            float z = ldv<F32>(fhP, p * (HH * OO) + h * OO + o);
            float w = (step == 0) ? 1.f : (step == 1 ? cA[p * OO + o] : c2[p * OO + o]);
            v += w * z;
        }
        ZcnS[n * HH + h] = (short)f2bf(v);
    }
    for (int i = blockIdx.x * 256 + tid; i < DIN * HH; i += 16 * 256) {
        int h = i >> 7, k = i & 127;
        WtS[h * DIN + k] = (short)f2bf(ldv<F32>(WP, k * HH + h));  // W_in^T
    }
}

__global__ void k1_prep(const void* fhP, const void* ahP, const void* WP,
                        short* ZcnS, short* WtS, double* dstats,
                        const void* featP, int* flag) {
    __shared__ float cA[MM * OO];
    __shared__ float c2[MM * OO];
    __shared__ int chuge, czero, sflag;
    const int tid = threadIdx.x;
    if (tid == 0) { chuge = 0; czero = 0; }
    if (blockIdx.x == 0 && tid < 64) dstats[tid] = 0.0;
    __syncthreads();
    if (tid < 64) {
        const unsigned short* p = (const unsigned short*)featP;
        int h = 0, z = 0;
        for (int i = tid; i < 4096; i += 64) {
            unsigned short u = p[i];
            unsigned e = (u >> 7) & 0xFFu;
            if (e >= 0x90u) h++;             // |v| >= 2^17: impossible for N(0,1)
            if ((u & 0x7FFFu) == 0) z++;     // exact zero
        }
        atomicAdd(&chuge, h);
        atomicAdd(&czero, z);
    }
    __syncthreads();
    if (tid == 0) {
        sflag = (chuge > 8 || czero > 512) ? 1 : 0;
        if (blockIdx.x == 0) *flag = sflag;  // for k2/k4
    }
    __syncthreads();
    if (sflag) k1_body<true>(fhP, ahP, WP, ZcnS, WtS, cA, c2);
    else       k1_body<false>(fhP, ahP, WP, ZcnS, WtS, cA, c2);
}

// --------------------------- K2: main kernel -------------------------------
// One wave per batch element per iteration. 512 blocks * 4 waves = 2048 waves,
// grid-stride *16. x0buf is WAVE-PRIVATE: ordering inside the loop needs only
// __threadfence_block (lgkmcnt, compile-time order) — NOT __syncthreads,
// whose vmcnt(0) drain would stall the global-load pipeline every iteration.
// MFMA 16x16x32 bf16:
//   A-frag: A[m=lane&15][k=(lane>>4)*8+j], B-frag: B[k=(lane>>4)*8+j][n=lane&15]
//   C/D:    C[row=(lane>>4)*4+reg][col=lane&15]   (m89-verified)
template<bool F32>
__device__ void k2_body(const void* adjP, const void* featP, const void* binP,
                        const short* ZcnS, const short* WtS, float* accOut,
                        double* dstats, short* myx0, float* bsum, float* bsqs) {
    const int tid  = threadIdx.x;
    const int lane = tid & 63;
    const int hl   = lane & 15;
    const int q    = lane >> 4;

    // persistent B-frags: W (16) + Zcn (12), loaded once
    vec8s Wfrag[4][4];
    for (int kt = 0; kt < 4; ++kt)
        for (int nt = 0; nt < 4; ++nt)
            Wfrag[kt][nt] = *(const vec8s*)(WtS + (nt * 16 + hl) * DIN + kt * 32 + q * 8);
    vec8s Zfrag[2][6];
    for (int kt = 0; kt < 2; ++kt)
        for (int t = 0; t < 6; ++t)
            Zfrag[kt][t] = *(const vec8s*)(ZcnS + (t * 16 + hl) * HH + kt * 32 + q * 8);
    float biasv[4];
    for (int nt = 0; nt < 4; ++nt) biasv[nt] = ldv<F32>(binP, nt * 16 + hl);

    const f32x4 z4 = {0.f, 0.f, 0.f, 0.f};
    float ls = 0.f, lss = 0.f;
    const int wgid = blockIdx.x * 4 + (tid >> 6);

    for (int b = wgid; b < NB; b += 2048) {
        // ---- loads: adj row chunk + features A-frags ----
        float a0, a1, a2, a3;
        vec8s af[4];
        if (F32) {
            f32x4 av = *(const f32x4*)((const float*)adjP + b * (SS * SS) + lane * 4);
            a0 = av[0]; a1 = av[1]; a2 = av[2]; a3 = av[3];
            const float* fb = (const float*)featP + b * (SS * DIN) + hl * DIN + q * 8;
            for (int kt = 0; kt < 4; ++kt) {
                f32x4 lo = *(const f32x4*)(fb + kt * 32);
                f32x4 hi = *(const f32x4*)(fb + kt * 32 + 4);
                af[kt] = pack8(lo, hi);
            }
        } else {
            vec4s av = *(const vec4s*)((const short*)adjP + b * (SS * SS) + lane * 4);
            a0 = bf2f((unsigned short)av.x); a1 = bf2f((unsigned short)av.y);
            a2 = bf2f((unsigned short)av.z); a3 = bf2f((unsigned short)av.w);
            const short* fb = (const short*)featP + b * (SS * DIN) + hl * DIN + q * 8;
            for (int kt = 0; kt < 4; ++kt) af[kt] = *(const vec8s*)(fb + kt * 32);
        }

        // ---- r = rowsum(adj), w2 = r @ adj (adj symmetric) ----
        // lane holds adj[i][4c+t], i=lane>>2, c=lane&3
        float rsum = a0 + a1 + a2 + a3;
        rsum += __shfl_xor(rsum, 1);
        rsum += __shfl_xor(rsum, 2);            // r[i] at lanes 4i..4i+3
        int cg = lane & 3;
        float rr0 = __shfl(rsum, cg * 16 + 0);  // r[4c+t] lives at lane (4c+t)*4
        float rr1 = __shfl(rsum, cg * 16 + 4);
        float rr2 = __shfl(rsum, cg * 16 + 8);
        float rr3 = __shfl(rsum, cg * 16 + 12);
        float p = a0 * rr0 + a1 * rr1 + a2 * rr2 + a3 * rr3;
        p += __shfl_xor(p, 1);
        p += __shfl_xor(p, 2);                  // w2[i]
        float w1q[4], w2q[4];                   // weights for s = q*4+reg (C rows)
        for (int reg = 0; reg < 4; ++reg) {
            int src = q * 16 + reg * 4;
            w1q[reg] = __shfl(rsum, src);
            w2q[reg] = __shfl(p, src);
        }

        // ---- GEMM1: x0pre = F @ W_in   (16x128 @ 128x64, 16 MFMAs) ----
        f32x4 c1[4] = {z4, z4, z4, z4};
        for (int nt = 0; nt < 4; ++nt)
            for (int kt = 0; kt < 4; ++kt)
                c1[nt] = __builtin_amdgcn_mfma_f32_16x16x32_bf16(af[kt], Wfrag[kt][nt], c1[nt], 0, 0, 0);

        // ---- sigmoid -> bf16, transpose C-layout -> (s,h) rows in LDS ----
        for (int nt = 0; nt < 4; ++nt)
            for (int reg = 0; reg < 4; ++reg) {
                float x = c1[nt][reg] + biasv[nt];
                float sg = 1.f / (1.f + __expf(-x));
                unsigned int u = __float_as_uint(sg) + 0x8000u;   // half-up
                myx0[(q * 4 + reg) * 72 + nt * 16 + hl] = (short)(u >> 16);
            }
        __threadfence_block();   // order stores -> frag reads (wave-private LDS)

        // ---- GEMM2: P = x0 @ Zcn^T   (16x64 @ 64x96, 12 MFMAs) ----
        vec8s a2lo = *(const vec8s*)(myx0 + hl * 72 + q * 8);
        vec8s a2hi = *(const vec8s*)(myx0 + hl * 72 + 32 + q * 8);
        __threadfence_block();   // order frag reads -> next iter's stores (WAR)
        f32x4 cp[6] = {z4, z4, z4, z4, z4, z4};
        for (int t = 0; t < 6; ++t)
            cp[t] = __builtin_amdgcn_mfma_f32_16x16x32_bf16(a2lo, Zfrag[0][t], cp[t], 0, 0, 0);
        for (int t = 0; t < 6; ++t)
            cp[t] = __builtin_amdgcn_mfma_f32_16x16x32_bf16(a2hi, Zfrag[1][t], cp[t], 0, 0, 0);

        // ---- weighted s-reduction per tile t; n' = t*16+hl, step = t>>1 ----
        float parts[6];
        for (int t = 0; t < 6; ++t) {
            int step = t >> 1;
            float v;
            if (step == 0)      v = cp[t][0] + cp[t][1] + cp[t][2] + cp[t][3];
            else if (step == 1) v = cp[t][0]*w1q[0] + cp[t][1]*w1q[1] + cp[t][2]*w1q[2] + cp[t][3]*w1q[3];
            else                v = cp[t][0]*w2q[0] + cp[t][1]*w2q[1] + cp[t][2]*w2q[2] + cp[t][3]*w2q[3];
            v += __shfl_xor(v, 16);
            v += __shfl_xor(v, 32);
            parts[t] = v;
        }
        float accA = parts[0] + parts[2] + parts[4];   // o = hl
        float accB = parts[1] + parts[3] + parts[5];   // o = 16 + hl
        float accv = ((lane >> 4) & 1) ? accB : accA;  // o = lane & 31 (dup x2)
        accv *= (1.f / 3.f);
        accv = __builtin_isnan(accv) ? 0.f : accv;     // diagnostic net
        if (lane < OO) accOut[b * OO + lane] = accv;
        ls  += accv;
        lss += accv * accv;
    }

    // ---- BN batch statistics: wave -> block(LDS) -> global(fp64 atomics) ----
    if (lane < OO) {
        atomicAdd(&bsum[lane], ls);
        atomicAdd(&bsqs[lane], lss);
    }
    __syncthreads();
    if (tid < OO) {
        atomicAdd(&dstats[tid],      (double)bsum[tid]);
        atomicAdd(&dstats[OO + tid], (double)bsqs[tid]);
    }
}

__global__ __launch_bounds__(256, 2) void k2_main(
    const void* adjP, const void* featP, const void* binP,
    const short* ZcnS, const short* WtS, float* accOut,
    double* dstats, const int* flag) {
    __shared__ __align__(16) short x0buf[4][SS * 72];
    __shared__ float bsum[OO];
    __shared__ float bsqs[OO];
    const int tid = threadIdx.x;
    if (tid < OO) { bsum[tid] = 0.f; bsqs[tid] = 0.f; }
    __syncthreads();
    short* myx0 = x0buf[tid >> 6];
    if (*flag) k2_body<true>(adjP, featP, binP, ZcnS, WtS, accOut, dstats, myx0, bsum, bsqs);
    else       k2_body<false>(adjP, featP, binP, ZcnS, WtS, accOut, dstats, myx0, bsum, bsqs);
}

// ------------------- K4: BN stats finalize + apply + sigmoid ---------------
// Each block redundantly computes scale/shift from dstats (32 fp64 values).
__global__ __launch_bounds__(256) void k4_out(const float* __restrict__ acc,
                                              const double* __restrict__ dstats,
                                              const void* gammaP, const void* betaP,
                                              void* out, const int* flag) {
    __shared__ float sScale[OO], sShift[OO];
    const int tid = threadIdx.x;
    const int f = *flag;
    if (tid < OO) {
        double mean = dstats[tid] * (1.0 / (double)NB);
        double ex2  = dstats[OO + tid] * (1.0 / (double)NB);
        double var  = ex2 - mean * mean;
        if (var < 0.0) var = 0.0;
        double inv  = 1.0 / sqrt(var + 1e-5);
        float g  = f ? ldv<true>(gammaP, tid) : ldv<false>(gammaP, tid);
        float be = f ? ldv<true>(betaP, tid)  : ldv<false>(betaP, tid);
        sScale[tid] = g * (float)inv;
        sShift[tid] = be - (float)(mean * inv) * g;
    }
    __syncthreads();
    int i = (blockIdx.x * 256 + tid) * 4;
    int o0 = i & 31;
    f32x4 a = *(const f32x4*)(acc + i);
    float r[4];
    for (int j = 0; j < 4; ++j) {
        float z = a[j] * sScale[o0 + j] + sShift[o0 + j];
        r[j] = 1.f / (1.f + __expf(-z));
    }
    if (f) {
        f32x4 w;
        for (int j = 0; j < 4; ++j) w[j] = r[j];
        *(f32x4*)((float*)out + i) = w;
    } else {
        vec4us w;
        for (int j = 0; j < 4; ++j) w[j] = f2bf(r[j]);
        *(vec4us*)((unsigned short*)out + i) = w;
    }
}

// ---------------------------------------------------------------------------
extern "C" void kernel_launch(void* const* d_in, const int* in_sizes, int n_in,
                              void* d_out, int out_size, void* d_ws, size_t ws_size,
                              hipStream_t stream) {
    const void* adjP   = d_in[0];  // (B,16,16)
    const void* featP  = d_in[1];  // (B,16,128)
    const void* WP     = d_in[2];  // (128,64)
    const void* binP   = d_in[3];  // (64,)
    const void* fhP    = d_in[4];  // (16,64,32)
    const void* ahP    = d_in[5];  // (120,32)
    const void* gammaP = d_in[6];  // (32,)
    const void* betaP  = d_in[7];  // (32,)

    char* ws = (char*)d_ws;
    float*  accOut   = (float*)(ws);                    // 32768*32*4 = 4194304 B
    short*  ZcnS     = (short*)(ws + 4194304);          // 96*64*2   = 12288 B
    short*  WtS      = (short*)(ws + 4206592);          // 64*128*2  = 16384 B
    double* dstats   = (double*)(ws + 4222976);         // 64*8      = 512 B
    int*    flag     = (int*)(ws + 4223744);            // 4 B

    hipLaunchKernelGGL(k1_prep,  dim3(16),   dim3(256), 0, stream,
                       fhP, ahP, WP, ZcnS, WtS, dstats, featP, flag);
    hipLaunchKernelGGL(k2_main,  dim3(512),  dim3(256), 0, stream,
                       adjP, featP, binP, ZcnS, WtS, accOut, dstats, flag);
    hipLaunchKernelGGL(k4_out,   dim3(1024), dim3(256), 0, stream,
                       accOut, dstats, gammaP, betaP, d_out, flag);
}